// Round 7
// baseline (49.188 us; speedup 1.0000x reference)
//
#include <hip/hip_runtime.h>

#define BB 2048          // batches
#define TT 4096          // timesteps
#define LN2 0.69314718055994530942f
#define ROWS 2           // batch rows per block (1024 blocks -> single generation)

// ---------------------------------------------------------------------------
// One-kernel CRF fold (round 7) = round-6 structure + amdgpu_waves_per_eu(4,4).
// Session lesson: __launch_bounds__'s 2nd arg is only a MIN waves/EU (a VGPR
// ceiling); hipcc's allocator still targets MAX occupancy (8 waves/EU = 64
// VGPR) and spills the rest. Every kernel this session ran at <=64 VGPRs
// (R0/R1:64, R2:32, R4:48, R6:64+55MB spill). waves_per_eu(4,4) pins BOTH
// bounds -> allocator may use up to 128 VGPRs spill-free, which is what the
// ROWS=2 pipeline (live set ~112) needs:
//   * ROWS=2: grid = 1024 blocks = 4/CU, all resident in ONE generation.
//   * row r+1's full 16-load clause issues after row r's last MATSTEP and
//     before row r's fold -> ~1000cy fold/tail hides ~900cy load latency.
//   * ordered shfl_down fold (self = left operand, no selects); lane 0 valid.
//   * thread 0 stashes v = exp(logits[b,0,:]) from its own clause.
// Failure signatures: VGPR=64 + MB spill -> attribute ineffective (revert R3);
// VGPR~128 no spill but flat perf -> pipeline theory wrong (keep R3).
// ---------------------------------------------------------------------------
__global__ __launch_bounds__(256)
__attribute__((amdgpu_waves_per_eu(4, 4)))
void crf_pass1(
    const float* __restrict__ logits, const float* __restrict__ trans,
    const int* __restrict__ tags, float* __restrict__ ws)
{
    __shared__ float sTrans[9];
    __shared__ float sTrExp[9];
    __shared__ float sRec[3][12];      // records of waves 1..3
    const int tid = threadIdx.x;
    if (tid < 9) {
        float tv = trans[tid];
        sTrans[tid] = tv;
        sTrExp[tid] = __expf(tv);
    }
    __syncthreads();

    const int c  = tid;                // chunk index within a row
    const int b0 = blockIdx.x * ROWS;

    // ---- prologue: issue row-0 clause (tags first, then logits) ----
    int4  Tq[4];
    float Lf[48];
    {
        const int4*   tp = (const int4*)(tags + (size_t)b0 * TT + (size_t)c * 16);
        const float4* lp = (const float4*)(logits + ((size_t)b0 * TT + (size_t)c * 16) * 3);
#pragma unroll
        for (int i = 0; i < 4; ++i) Tq[i] = tp[i];
#pragma unroll
        for (int i = 0; i < 12; ++i) {
            float4 t = lp[i];
            Lf[4*i+0] = t.x; Lf[4*i+1] = t.y; Lf[4*i+2] = t.z; Lf[4*i+3] = t.w;
        }
    }
    __builtin_amdgcn_sched_barrier(0);

    const float t00 = sTrExp[0], t01 = sTrExp[1], t02 = sTrExp[2];
    const float t10 = sTrExp[3], t11 = sTrExp[4], t12 = sTrExp[5];
    const float t20 = sTrExp[6], t21 = sTrExp[7], t22 = sTrExp[8];

#define MATSTEP(e0_, e1_, e2_) do {                                     \
    float x0 = __expf(e0_), x1 = __expf(e1_), x2 = __expf(e2_);         \
    float b0_ = (a00*t00 + a01*t10 + a02*t20) * x0;                     \
    float b1_ = (a00*t01 + a01*t11 + a02*t21) * x1;                     \
    float b2_ = (a00*t02 + a01*t12 + a02*t22) * x2;                     \
    float b3_ = (a10*t00 + a11*t10 + a12*t20) * x0;                     \
    float b4_ = (a10*t01 + a11*t11 + a12*t21) * x1;                     \
    float b5_ = (a10*t02 + a11*t12 + a12*t22) * x2;                     \
    float b6_ = (a20*t00 + a21*t10 + a22*t20) * x0;                     \
    float b7_ = (a20*t01 + a21*t11 + a22*t21) * x1;                     \
    float b8_ = (a20*t02 + a21*t12 + a22*t22) * x2;                     \
    a00=b0_; a01=b1_; a02=b2_; a10=b3_; a11=b4_; a12=b5_; a20=b6_; a21=b7_; a22=b8_; \
} while (0)

#define RENORM do {                                                     \
    float m_ = fmaxf(fmaxf(fmaxf(a00, a01), fmaxf(a02, a10)),           \
                     fmaxf(fmaxf(a11, a12), fmaxf(fmaxf(a20, a21), a22))); \
    int ef_ = (int)(__float_as_uint(m_) >> 23);                         \
    float scf_ = __uint_as_float((unsigned)(254 - ef_) << 23);          \
    se += ef_ - 127;                                                    \
    a00 *= scf_; a01 *= scf_; a02 *= scf_;                              \
    a10 *= scf_; a11 *= scf_; a12 *= scf_;                              \
    a20 *= scf_; a21 *= scf_; a22 *= scf_;                              \
} while (0)

#pragma unroll
    for (int r = 0; r < ROWS; ++r) {
        const int b = b0 + r;

        // pack 16 tags (0..2) into one reg (Tq loaded long ago -> no stall)
        unsigned pk = 0;
#pragma unroll
        for (int i = 0; i < 4; ++i) {
            pk |= ((unsigned)Tq[i].x << (8*i))   | ((unsigned)Tq[i].y << (8*i+2))
                | ((unsigned)Tq[i].z << (8*i+4)) | ((unsigned)Tq[i].w << (8*i+6));
        }
        const int firstTag = (int)(pk & 3u);

        float a00 = 1.f, a01 = 0.f, a02 = 0.f;
        float a10 = 0.f, a11 = 1.f, a12 = 0.f;
        float a20 = 0.f, a21 = 0.f, a22 = 1.f;
        int   se = 0;
        float score = 0.f;
        unsigned long long acc = 0ull;   // 9 x 7-bit transition-pair counters
        int prev = 0;
        float v0 = 0.f, v1 = 0.f, v2 = 0.f;   // alpha0 (thread 0 of the row)

        // ---- 16 steps ----
#pragma unroll
        for (int s = 0; s < 16; ++s) {
            float e0 = Lf[3*s+0], e1 = Lf[3*s+1], e2 = Lf[3*s+2];
            int tg = (int)((pk >> (2*s)) & 3u);
            if (s == 0) {
                if (c == 0) {            // t=0 of this row: alpha0
                    v0 = __expf(e0); v1 = __expf(e1); v2 = __expf(e2);
                } else {
                    MATSTEP(e0, e1, e2);
                }
            } else {
                MATSTEP(e0, e1, e2);
                acc += 1ull << (7 * (prev * 3 + tg));
            }
            score += (tg == 0) ? e0 : ((tg == 1) ? e1 : e2);
            prev = tg;
            if ((s & 7) == 7) RENORM;
        }

        // ---- issue next row's clause NOW (Lf/Tq dead) — fold hides latency
        if (r + 1 < ROWS) {
            const int4*   tp2 = (const int4*)(tags + (size_t)(b + 1) * TT + (size_t)c * 16);
            const float4* lp2 = (const float4*)(logits + ((size_t)(b + 1) * TT + (size_t)c * 16) * 3);
#pragma unroll
            for (int i = 0; i < 4; ++i) Tq[i] = tp2[i];
#pragma unroll
            for (int i = 0; i < 12; ++i) {
                float4 t = lp2[i];
                Lf[4*i+0] = t.x; Lf[4*i+1] = t.y; Lf[4*i+2] = t.z; Lf[4*i+3] = t.w;
            }
        }
        __builtin_amdgcn_sched_barrier(0);

        // fold transition-pair counts into score (max count 15 < 127)
#pragma unroll
        for (int p = 0; p < 9; ++p)
            score += (float)((int)((acc >> (7 * p)) & 127ull)) * sTrans[p];

        // ---- ordered shfl_down fold of 64 chunk records (lane 0 ends valid)
        int fT = firstTag;               // mutable copy for the fold
        int fp = fT | (prev << 8);       // packed firstTag|last for shuffling
#pragma unroll
        for (int m = 1; m < 64; m <<= 1) {
            float o00 = __shfl_down(a00, m, 64), o01 = __shfl_down(a01, m, 64), o02 = __shfl_down(a02, m, 64);
            float o10 = __shfl_down(a10, m, 64), o11 = __shfl_down(a11, m, 64), o12 = __shfl_down(a12, m, 64);
            float o20 = __shfl_down(a20, m, 64), o21 = __shfl_down(a21, m, 64), o22 = __shfl_down(a22, m, 64);
            int   ose = __shfl_down(se, m, 64);
            float osc = __shfl_down(score, m, 64);
            int   ofp = __shfl_down(fp, m, 64);   // right block's firstTag|last

            // C = self(left) x other(right); no selects
            float c00 = a00*o00 + a01*o10 + a02*o20;
            float c01 = a00*o01 + a01*o11 + a02*o21;
            float c02 = a00*o02 + a01*o12 + a02*o22;
            float c10 = a10*o00 + a11*o10 + a12*o20;
            float c11 = a10*o01 + a11*o11 + a12*o21;
            float c12 = a10*o02 + a11*o12 + a12*o22;
            float c20 = a20*o00 + a21*o10 + a22*o20;
            float c21 = a20*o01 + a21*o11 + a22*o21;
            float c22 = a20*o02 + a21*o12 + a22*o22;

            score = score + osc + sTrans[(fp >> 8) * 3 + (ofp & 255)]; // seam
            fp = (fp & 255) | (ofp & ~255);     // keep left first, take right last
            se += ose;

            a00=c00; a01=c01; a02=c02; a10=c10; a11=c11; a12=c12; a20=c20; a21=c21; a22=c22;
            RENORM;
        }
        prev = fp >> 8;
        fT   = fp & 255;

        // ---- cross-wave fold (waves are time-ordered) ----
        const int lane = tid & 63;
        const int wid  = tid >> 6;
        __syncthreads();                 // sRec safe to overwrite (prev row done)
        if (lane == 0 && wid > 0) {
            sRec[wid-1][0] = a00; sRec[wid-1][1] = a01; sRec[wid-1][2] = a02;
            sRec[wid-1][3] = a10; sRec[wid-1][4] = a11; sRec[wid-1][5] = a12;
            sRec[wid-1][6] = a20; sRec[wid-1][7] = a21; sRec[wid-1][8] = a22;
            sRec[wid-1][9]  = __int_as_float(se);
            sRec[wid-1][10] = score;
            sRec[wid-1][11] = __int_as_float(fT | (prev << 8));
        }
        __syncthreads();
        if (tid == 0) {
#pragma unroll
            for (int k = 0; k < 3; ++k) {
                float m00 = sRec[k][0], m01 = sRec[k][1], m02 = sRec[k][2];
                float m10 = sRec[k][3], m11 = sRec[k][4], m12 = sRec[k][5];
                float m20 = sRec[k][6], m21 = sRec[k][7], m22 = sRec[k][8];
                int   shm = __float_as_int(sRec[k][9]);
                float scm = sRec[k][10];
                int   pkm = __float_as_int(sRec[k][11]);

                float c00 = a00*m00 + a01*m10 + a02*m20;
                float c01 = a00*m01 + a01*m11 + a02*m21;
                float c02 = a00*m02 + a01*m12 + a02*m22;
                float c10 = a10*m00 + a11*m10 + a12*m20;
                float c11 = a10*m01 + a11*m11 + a12*m21;
                float c12 = a10*m02 + a11*m12 + a12*m22;
                float c20 = a20*m00 + a21*m10 + a22*m20;
                float c21 = a20*m01 + a21*m11 + a22*m21;
                float c22 = a20*m02 + a21*m12 + a22*m22;

                score += scm + sTrans[prev * 3 + (pkm & 255)];
                prev = pkm >> 8;
                se += shm;
                a00=c00; a01=c01; a02=c02; a10=c10; a11=c11; a12=c12; a20=c20; a21=c21; a22=c22;
                RENORM;
            }
            // alpha_T = v . P (row-vector times total product), value * 2^se
            float n0 = v0*a00 + v1*a10 + v2*a20;
            float n1 = v0*a01 + v1*a11 + v2*a21;
            float n2 = v0*a02 + v1*a12 + v2*a22;
            float logz = logf(n0 + n1 + n2) + (float)se * LN2;
            ws[b] = logz - score;        // per-batch nll
        }
    }

#undef MATSTEP
#undef RENORM
}

// ---------------------------------------------------------------------------
// Final reduction: one block sums the 2048 per-batch nll values.
// ---------------------------------------------------------------------------
__global__ __launch_bounds__(256) void crf_reduce(
    const float* __restrict__ ws, float* __restrict__ out)
{
    int tid = threadIdx.x;
    float s = 0.f;
#pragma unroll
    for (int k = 0; k < BB / 256; ++k) s += ws[k * 256 + tid];
    for (int off = 32; off > 0; off >>= 1) s += __shfl_down(s, off, 64);
    __shared__ float sP[4];
    if ((tid & 63) == 0) sP[tid >> 6] = s;
    __syncthreads();
    if (tid == 0) out[0] = sP[0] + sP[1] + sP[2] + sP[3];
}

extern "C" void kernel_launch(void* const* d_in, const int* in_sizes, int n_in,
                              void* d_out, int out_size, void* d_ws, size_t ws_size,
                              hipStream_t stream) {
    const float* logits = (const float*)d_in[0];
    const float* trans  = (const float*)d_in[1];
    const int*   tags   = (const int*)d_in[2];
    float* out = (float*)d_out;
    float* ws  = (float*)d_ws;

    crf_pass1<<<dim3(BB / ROWS), dim3(256), 0, stream>>>(logits, trans, tags, ws);
    crf_reduce<<<dim3(1), dim3(256), 0, stream>>>(ws, out);
}

// Round 8
// 36.160 us; speedup vs baseline: 1.3603x; 1.3603x over previous
//
#include <hip/hip_runtime.h>

#define BB 2048          // batches
#define TT 4096          // timesteps
#define LN2 0.69314718055994530942f

// ---------------------------------------------------------------------------
// One-kernel CRF fold (round 8): designed for the HARD 64-VGPR budget.
// Session law (R2/R4/R5/R6/R7): hipcc pins this kernel at 64 VGPRs regardless
// of launch_bounds / amdgpu_waves_per_eu (attribute reached codegen — SGPR
// changed — but VGPR stayed 64 and spills remained). So the kernel must have
// live-set <= 64:
//   * 8 steps/thread (not 16): clause = 6 float4 logits + 2 int4 tags.
//     Live set ~54 steady / ~66 peak -> fits; no spill.
//   * block = 512 threads = ONE batch row (512 x 8 = 4096 steps).
//     Default allocator target (8 waves/EU) now WORKS: 32 waves/CU, 4
//     blocks/CU, grid = 2048 blocks = 2 generations (R3 had 8).
//   * transition counters in ONE 32-bit reg (9 fields x 3 bits, max 7/field).
//   * ordered shfl_down fold (self = left operand, no selects); lane 0 valid;
//     cross-wave fold over 7 LDS records; tid 0 writes per-batch nll.
// ---------------------------------------------------------------------------
__global__ __launch_bounds__(512) void crf_pass1(
    const float* __restrict__ logits, const float* __restrict__ trans,
    const int* __restrict__ tags, float* __restrict__ ws)
{
    __shared__ float sTrans[9];
    __shared__ float sTrExp[9];
    __shared__ float sRec[7][12];      // records of waves 1..7
    const int tid = threadIdx.x;
    if (tid < 9) {
        float tv = trans[tid];
        sTrans[tid] = tv;
        sTrExp[tid] = __expf(tv);
    }
    __syncthreads();

    const int b = blockIdx.x;
    const int c = tid;                 // chunk index: steps [8c, 8c+8)

    const int4*   tp = (const int4*)(tags + (size_t)b * TT + (size_t)c * 8);
    const float4* lp = (const float4*)(logits + ((size_t)b * TT + (size_t)c * 8) * 3);

    // ---- issue the full clause: tags first, then logits ----
    int4 Tq0 = tp[0], Tq1 = tp[1];
    float Lf[24];
#pragma unroll
    for (int i = 0; i < 6; ++i) {
        float4 t = lp[i];
        Lf[4*i+0] = t.x; Lf[4*i+1] = t.y; Lf[4*i+2] = t.z; Lf[4*i+3] = t.w;
    }
    __builtin_amdgcn_sched_barrier(0);   // whole clause issued before any use

    // pack 8 tags (0..2) into one reg; waits vmcnt(6) (logits still in flight)
    unsigned pk =  (unsigned)Tq0.x        | ((unsigned)Tq0.y << 2)
                | ((unsigned)Tq0.z << 4)  | ((unsigned)Tq0.w << 6)
                | ((unsigned)Tq1.x << 8)  | ((unsigned)Tq1.y << 10)
                | ((unsigned)Tq1.z << 12) | ((unsigned)Tq1.w << 14);

    const float t00 = sTrExp[0], t01 = sTrExp[1], t02 = sTrExp[2];
    const float t10 = sTrExp[3], t11 = sTrExp[4], t12 = sTrExp[5];
    const float t20 = sTrExp[6], t21 = sTrExp[7], t22 = sTrExp[8];

    float a00 = 1.f, a01 = 0.f, a02 = 0.f;
    float a10 = 0.f, a11 = 1.f, a12 = 0.f;
    float a20 = 0.f, a21 = 0.f, a22 = 1.f;
    int   se = 0;
    float score = 0.f;
    unsigned acc = 0u;                 // 9 x 3-bit transition-pair counters
    int prev = 0;
    float v0 = 0.f, v1 = 0.f, v2 = 0.f;   // alpha0 (thread 0 only)

#define MATSTEP(e0_, e1_, e2_) do {                                     \
    float x0 = __expf(e0_), x1 = __expf(e1_), x2 = __expf(e2_);         \
    float b0_ = (a00*t00 + a01*t10 + a02*t20) * x0;                     \
    float b1_ = (a00*t01 + a01*t11 + a02*t21) * x1;                     \
    float b2_ = (a00*t02 + a01*t12 + a02*t22) * x2;                     \
    float b3_ = (a10*t00 + a11*t10 + a12*t20) * x0;                     \
    float b4_ = (a10*t01 + a11*t11 + a12*t21) * x1;                     \
    float b5_ = (a10*t02 + a11*t12 + a12*t22) * x2;                     \
    float b6_ = (a20*t00 + a21*t10 + a22*t20) * x0;                     \
    float b7_ = (a20*t01 + a21*t11 + a22*t21) * x1;                     \
    float b8_ = (a20*t02 + a21*t12 + a22*t22) * x2;                     \
    a00=b0_; a01=b1_; a02=b2_; a10=b3_; a11=b4_; a12=b5_; a20=b6_; a21=b7_; a22=b8_; \
} while (0)

#define RENORM do {                                                     \
    float m_ = fmaxf(fmaxf(fmaxf(a00, a01), fmaxf(a02, a10)),           \
                     fmaxf(fmaxf(a11, a12), fmaxf(fmaxf(a20, a21), a22))); \
    int ef_ = (int)(__float_as_uint(m_) >> 23);                         \
    float scf_ = __uint_as_float((unsigned)(254 - ef_) << 23);          \
    se += ef_ - 127;                                                    \
    a00 *= scf_; a01 *= scf_; a02 *= scf_;                              \
    a10 *= scf_; a11 *= scf_; a12 *= scf_;                              \
    a20 *= scf_; a21 *= scf_; a22 *= scf_;                              \
} while (0)

    // ---- 8 steps ----
#pragma unroll
    for (int s = 0; s < 8; ++s) {
        float e0 = Lf[3*s+0], e1 = Lf[3*s+1], e2 = Lf[3*s+2];
        int tg = (int)((pk >> (2*s)) & 3u);
        if (s == 0) {
            if (c == 0) {              // t=0: alpha0, no transition step
                v0 = __expf(e0); v1 = __expf(e1); v2 = __expf(e2);
            } else {
                MATSTEP(e0, e1, e2);
            }
        } else {
            MATSTEP(e0, e1, e2);
            acc += 1u << (3 * (prev * 3 + tg));   // max 7 per field
        }
        score += (tg == 0) ? e0 : ((tg == 1) ? e1 : e2);
        prev = tg;
    }
    RENORM;

    // fold transition-pair counts into score
#pragma unroll
    for (int p = 0; p < 9; ++p)
        score += (float)((int)((acc >> (3 * p)) & 7u)) * sTrans[p];

    // ---- ordered shfl_down fold of 64 chunk records (lane 0 ends valid) ----
    int fp = (int)(pk & 3u) | (prev << 8);   // packed firstTag|last
#pragma unroll
    for (int m = 1; m < 64; m <<= 1) {
        float o00 = __shfl_down(a00, m, 64), o01 = __shfl_down(a01, m, 64), o02 = __shfl_down(a02, m, 64);
        float o10 = __shfl_down(a10, m, 64), o11 = __shfl_down(a11, m, 64), o12 = __shfl_down(a12, m, 64);
        float o20 = __shfl_down(a20, m, 64), o21 = __shfl_down(a21, m, 64), o22 = __shfl_down(a22, m, 64);
        int   ose = __shfl_down(se, m, 64);
        float osc = __shfl_down(score, m, 64);
        int   ofp = __shfl_down(fp, m, 64);   // right block's firstTag|last

        // C = self(left) x other(right); no selects
        float c00 = a00*o00 + a01*o10 + a02*o20;
        float c01 = a00*o01 + a01*o11 + a02*o21;
        float c02 = a00*o02 + a01*o12 + a02*o22;
        float c10 = a10*o00 + a11*o10 + a12*o20;
        float c11 = a10*o01 + a11*o11 + a12*o21;
        float c12 = a10*o02 + a11*o12 + a12*o22;
        float c20 = a20*o00 + a21*o10 + a22*o20;
        float c21 = a20*o01 + a21*o11 + a22*o21;
        float c22 = a20*o02 + a21*o12 + a22*o22;

        score = score + osc + sTrans[(fp >> 8) * 3 + (ofp & 255)];  // seam
        fp = (fp & 255) | (ofp & ~255);    // keep left first, take right last
        se += ose;

        a00=c00; a01=c01; a02=c02; a10=c10; a11=c11; a12=c12; a20=c20; a21=c21; a22=c22;
        RENORM;
    }
    prev = fp >> 8;

    // ---- cross-wave fold (8 waves, time-ordered) ----
    const int lane = tid & 63;
    const int wid  = tid >> 6;
    if (lane == 0 && wid > 0) {
        sRec[wid-1][0] = a00; sRec[wid-1][1] = a01; sRec[wid-1][2] = a02;
        sRec[wid-1][3] = a10; sRec[wid-1][4] = a11; sRec[wid-1][5] = a12;
        sRec[wid-1][6] = a20; sRec[wid-1][7] = a21; sRec[wid-1][8] = a22;
        sRec[wid-1][9]  = __int_as_float(se);
        sRec[wid-1][10] = score;
        sRec[wid-1][11] = __int_as_float(fp);
    }
    __syncthreads();
    if (tid == 0) {
#pragma unroll
        for (int k = 0; k < 7; ++k) {
            float m00 = sRec[k][0], m01 = sRec[k][1], m02 = sRec[k][2];
            float m10 = sRec[k][3], m11 = sRec[k][4], m12 = sRec[k][5];
            float m20 = sRec[k][6], m21 = sRec[k][7], m22 = sRec[k][8];
            int   shm = __float_as_int(sRec[k][9]);
            float scm = sRec[k][10];
            int   pkm = __float_as_int(sRec[k][11]);

            float c00 = a00*m00 + a01*m10 + a02*m20;
            float c01 = a00*m01 + a01*m11 + a02*m21;
            float c02 = a00*m02 + a01*m12 + a02*m22;
            float c10 = a10*m00 + a11*m10 + a12*m20;
            float c11 = a10*m01 + a11*m11 + a12*m21;
            float c12 = a10*m02 + a11*m12 + a12*m22;
            float c20 = a20*m00 + a21*m10 + a22*m20;
            float c21 = a20*m01 + a21*m11 + a22*m21;
            float c22 = a20*m02 + a21*m12 + a22*m22;

            score += scm + sTrans[prev * 3 + (pkm & 255)];
            prev = pkm >> 8;
            se += shm;
            a00=c00; a01=c01; a02=c02; a10=c10; a11=c11; a12=c12; a20=c20; a21=c21; a22=c22;
            RENORM;
        }
        // alpha_T = v . P (row-vector times total product), value * 2^se
        float n0 = v0*a00 + v1*a10 + v2*a20;
        float n1 = v0*a01 + v1*a11 + v2*a21;
        float n2 = v0*a02 + v1*a12 + v2*a22;
        float logz = logf(n0 + n1 + n2) + (float)se * LN2;
        ws[b] = logz - score;          // per-batch nll
    }

#undef MATSTEP
#undef RENORM
}

// ---------------------------------------------------------------------------
// Final reduction: one block sums the 2048 per-batch nll values.
// ---------------------------------------------------------------------------
__global__ __launch_bounds__(256) void crf_reduce(
    const float* __restrict__ ws, float* __restrict__ out)
{
    int tid = threadIdx.x;
    float s = 0.f;
#pragma unroll
    for (int k = 0; k < BB / 256; ++k) s += ws[k * 256 + tid];
    for (int off = 32; off > 0; off >>= 1) s += __shfl_down(s, off, 64);
    __shared__ float sP[4];
    if ((tid & 63) == 0) sP[tid >> 6] = s;
    __syncthreads();
    if (tid == 0) out[0] = sP[0] + sP[1] + sP[2] + sP[3];
}

extern "C" void kernel_launch(void* const* d_in, const int* in_sizes, int n_in,
                              void* d_out, int out_size, void* d_ws, size_t ws_size,
                              hipStream_t stream) {
    const float* logits = (const float*)d_in[0];
    const float* trans  = (const float*)d_in[1];
    const int*   tags   = (const int*)d_in[2];
    float* out = (float*)d_out;
    float* ws  = (float*)d_ws;

    crf_pass1<<<dim3(BB), dim3(512), 0, stream>>>(logits, trans, tags, ws);
    crf_reduce<<<dim3(1), dim3(256), 0, stream>>>(ws, out);
}

// Round 9
// 32.591 us; speedup vs baseline: 1.5093x; 1.1095x over previous
//
#include <hip/hip_runtime.h>

#define BB 2048          // batches
#define TT 4096          // timesteps
#define LN2 0.69314718055994530942f

// ---------------------------------------------------------------------------
// One-kernel CRF fold (round 9) = round-8 envelope + DPP (zero-DS) wave fold.
// R8 post-mortem: the ordered shfl_down fold = 72 ds_bpermute per wave-row on
// the single per-CU LDS unit ~= 11 us/CU at 8 waves/row (R8-R3 delta matched
// the fold doubling). This round replaces ALL fold shuffles with the classic
// gfx9 DPP ladder (row_shr:1/2/4/8, row_bcast:15, row_bcast:31 -> result in
// lane 63). Non-commutativity: the DPP operand comes from LOWER lanes =
// earlier chunks = always the LEFT matrix factor. update_dpp(old=0,
// bound_ctrl=1) zeroes invalid lanes: +0 for score/se sums (correct), zero
// matrices in lanes whose results are never consumed (traced: the lane-63
// chain only reads lanes 47/31/15/... which are valid at their round).
// Seam transitions leave the fold: one __shfl_up(prev,1) per thread adds
// sTrans[last(c-1)][first(c)] up front; cross-wave seams in the tid-511 tail.
// Envelope unchanged from R8 (hard 64-VGPR law): 8 steps/thread, 512-thread
// block = one row, 32 waves/CU, no spill.
// ---------------------------------------------------------------------------
template<int CTRL>
__device__ __forceinline__ float dppf(float x) {
    return __int_as_float(__builtin_amdgcn_update_dpp(
        0, __float_as_int(x), CTRL, 0xF, 0xF, true));
}
template<int CTRL>
__device__ __forceinline__ int dppi(int x) {
    return __builtin_amdgcn_update_dpp(0, x, CTRL, 0xF, 0xF, true);
}

__global__ __launch_bounds__(512) void crf_pass1(
    const float* __restrict__ logits, const float* __restrict__ trans,
    const int* __restrict__ tags, float* __restrict__ ws)
{
    __shared__ float sTrans[9];
    __shared__ float sTrExp[9];
    __shared__ float sRec[7][12];      // records of waves 0..6
    __shared__ float sV[3];            // alpha0 from tid 0
    const int tid = threadIdx.x;
    if (tid < 9) {
        float tv = trans[tid];
        sTrans[tid] = tv;
        sTrExp[tid] = __expf(tv);
    }
    __syncthreads();

    const int b = blockIdx.x;
    const int c = tid;                 // chunk index: steps [8c, 8c+8)

    const int4*   tp = (const int4*)(tags + (size_t)b * TT + (size_t)c * 8);
    const float4* lp = (const float4*)(logits + ((size_t)b * TT + (size_t)c * 8) * 3);

    // ---- issue the full clause: tags first, then logits ----
    int4 Tq0 = tp[0], Tq1 = tp[1];
    float Lf[24];
#pragma unroll
    for (int i = 0; i < 6; ++i) {
        float4 t = lp[i];
        Lf[4*i+0] = t.x; Lf[4*i+1] = t.y; Lf[4*i+2] = t.z; Lf[4*i+3] = t.w;
    }
    __builtin_amdgcn_sched_barrier(0);   // whole clause issued before any use

    // pack 8 tags (0..2) into one reg; waits vmcnt(6) (logits still in flight)
    unsigned pk =  (unsigned)Tq0.x        | ((unsigned)Tq0.y << 2)
                | ((unsigned)Tq0.z << 4)  | ((unsigned)Tq0.w << 6)
                | ((unsigned)Tq1.x << 8)  | ((unsigned)Tq1.y << 10)
                | ((unsigned)Tq1.z << 12) | ((unsigned)Tq1.w << 14);

    const float t00 = sTrExp[0], t01 = sTrExp[1], t02 = sTrExp[2];
    const float t10 = sTrExp[3], t11 = sTrExp[4], t12 = sTrExp[5];
    const float t20 = sTrExp[6], t21 = sTrExp[7], t22 = sTrExp[8];

    float a00 = 1.f, a01 = 0.f, a02 = 0.f;
    float a10 = 0.f, a11 = 1.f, a12 = 0.f;
    float a20 = 0.f, a21 = 0.f, a22 = 1.f;
    int   se = 0;
    float score = 0.f;
    unsigned acc = 0u;                 // 9 x 3-bit transition-pair counters
    int prev = 0;
    float v0 = 0.f, v1 = 0.f, v2 = 0.f;   // alpha0 (thread 0 only)

#define MATSTEP(e0_, e1_, e2_) do {                                     \
    float x0 = __expf(e0_), x1 = __expf(e1_), x2 = __expf(e2_);         \
    float b0_ = (a00*t00 + a01*t10 + a02*t20) * x0;                     \
    float b1_ = (a00*t01 + a01*t11 + a02*t21) * x1;                     \
    float b2_ = (a00*t02 + a01*t12 + a02*t22) * x2;                     \
    float b3_ = (a10*t00 + a11*t10 + a12*t20) * x0;                     \
    float b4_ = (a10*t01 + a11*t11 + a12*t21) * x1;                     \
    float b5_ = (a10*t02 + a11*t12 + a12*t22) * x2;                     \
    float b6_ = (a20*t00 + a21*t10 + a22*t20) * x0;                     \
    float b7_ = (a20*t01 + a21*t11 + a22*t21) * x1;                     \
    float b8_ = (a20*t02 + a21*t12 + a22*t22) * x2;                     \
    a00=b0_; a01=b1_; a02=b2_; a10=b3_; a11=b4_; a12=b5_; a20=b6_; a21=b7_; a22=b8_; \
} while (0)

#define RENORM do {                                                     \
    float m_ = fmaxf(fmaxf(fmaxf(a00, a01), fmaxf(a02, a10)),           \
                     fmaxf(fmaxf(a11, a12), fmaxf(fmaxf(a20, a21), a22))); \
    int ef_ = (int)(__float_as_uint(m_) >> 23);                         \
    float scf_ = __uint_as_float((unsigned)(254 - ef_) << 23);          \
    se += ef_ - 127;                                                    \
    a00 *= scf_; a01 *= scf_; a02 *= scf_;                              \
    a10 *= scf_; a11 *= scf_; a12 *= scf_;                              \
    a20 *= scf_; a21 *= scf_; a22 *= scf_;                              \
} while (0)

    // ---- 8 steps ----
#pragma unroll
    for (int s = 0; s < 8; ++s) {
        float e0 = Lf[3*s+0], e1 = Lf[3*s+1], e2 = Lf[3*s+2];
        int tg = (int)((pk >> (2*s)) & 3u);
        if (s == 0) {
            if (c == 0) {              // t=0: alpha0, no transition step
                v0 = __expf(e0); v1 = __expf(e1); v2 = __expf(e2);
            } else {
                MATSTEP(e0, e1, e2);
            }
        } else {
            MATSTEP(e0, e1, e2);
            acc += 1u << (3 * (prev * 3 + tg));   // max 7 per field
        }
        score += (tg == 0) ? e0 : ((tg == 1) ? e1 : e2);
        prev = tg;
    }
    RENORM;

    // fold transition-pair counts into score
#pragma unroll
    for (int p = 0; p < 9; ++p)
        score += (float)((int)((acc >> (3 * p)) & 7u)) * sTrans[p];

    const int lane = tid & 63;
    const int wid  = tid >> 6;

    // ---- in-wave seam: chunk c-1 -> c transition (lane 0 handled cross-wave)
    {
        int opv = __shfl_up(prev, 1, 64);
        if (lane != 0) score += sTrans[opv * 3 + (int)(pk & 3u)];
    }

    int fp = (int)(pk & 3u) | (prev << 8);   // packed firstTag | lastTag<<8

    // ---- DPP ordered fold: zero DS ops; lane 63 ends with the wave product.
    // DPP operand (lower lane) = LEFT factor; score/se are inclusive sums
    // (+0 from invalid lanes); fp: first from left, last stays own.
#define FOLD_ROUND(CTRL) do {                                           \
    float o00=dppf<CTRL>(a00), o01=dppf<CTRL>(a01), o02=dppf<CTRL>(a02);\
    float o10=dppf<CTRL>(a10), o11=dppf<CTRL>(a11), o12=dppf<CTRL>(a12);\
    float o20=dppf<CTRL>(a20), o21=dppf<CTRL>(a21), o22=dppf<CTRL>(a22);\
    int   ose=dppi<CTRL>(se);                                           \
    float osc=dppf<CTRL>(score);                                        \
    int   ofp=dppi<CTRL>(fp);                                           \
    float c00=o00*a00+o01*a10+o02*a20;                                  \
    float c01=o00*a01+o01*a11+o02*a21;                                  \
    float c02=o00*a02+o01*a12+o02*a22;                                  \
    float c10=o10*a00+o11*a10+o12*a20;                                  \
    float c11=o10*a01+o11*a11+o12*a21;                                  \
    float c12=o10*a02+o11*a12+o12*a22;                                  \
    float c20=o20*a00+o21*a10+o22*a20;                                  \
    float c21=o20*a01+o21*a11+o22*a21;                                  \
    float c22=o20*a02+o21*a12+o22*a22;                                  \
    score += osc; se += ose;                                            \
    fp = (ofp & 255) | (fp & 0xFF00);                                   \
    a00=c00; a01=c01; a02=c02; a10=c10; a11=c11; a12=c12;               \
    a20=c20; a21=c21; a22=c22;                                          \
    RENORM;                                                             \
} while (0)

    FOLD_ROUND(0x111);   // row_shr:1
    FOLD_ROUND(0x112);   // row_shr:2
    FOLD_ROUND(0x114);   // row_shr:4
    FOLD_ROUND(0x118);   // row_shr:8
    FOLD_ROUND(0x142);   // row_bcast:15
    FOLD_ROUND(0x143);   // row_bcast:31

    // ---- cross-wave fold (8 waves, time-ordered); combiner = tid 511 ----
    if (lane == 63 && wid < 7) {
        sRec[wid][0] = a00; sRec[wid][1] = a01; sRec[wid][2] = a02;
        sRec[wid][3] = a10; sRec[wid][4] = a11; sRec[wid][5] = a12;
        sRec[wid][6] = a20; sRec[wid][7] = a21; sRec[wid][8] = a22;
        sRec[wid][9]  = __int_as_float(se);
        sRec[wid][10] = score;
        sRec[wid][11] = __int_as_float(fp);
    }
    if (tid == 0) { sV[0] = v0; sV[1] = v1; sV[2] = v2; }
    __syncthreads();

    if (tid == 511) {                  // holds wave 7's product in registers
        float p00 = sRec[0][0], p01 = sRec[0][1], p02 = sRec[0][2];
        float p10 = sRec[0][3], p11 = sRec[0][4], p12 = sRec[0][5];
        float p20 = sRec[0][6], p21 = sRec[0][7], p22 = sRec[0][8];
        int   seT   = __float_as_int(sRec[0][9]);
        float scT   = sRec[0][10];
        int   lastT = __float_as_int(sRec[0][11]) >> 8;

#define RENORMP do {                                                    \
    float m_ = fmaxf(fmaxf(fmaxf(p00, p01), fmaxf(p02, p10)),           \
                     fmaxf(fmaxf(p11, p12), fmaxf(fmaxf(p20, p21), p22))); \
    int ef_ = (int)(__float_as_uint(m_) >> 23);                         \
    float scf_ = __uint_as_float((unsigned)(254 - ef_) << 23);          \
    seT += ef_ - 127;                                                   \
    p00 *= scf_; p01 *= scf_; p02 *= scf_;                              \
    p10 *= scf_; p11 *= scf_; p12 *= scf_;                              \
    p20 *= scf_; p21 *= scf_; p22 *= scf_;                              \
} while (0)

#pragma unroll
        for (int k = 1; k < 7; ++k) {
            float m00 = sRec[k][0], m01 = sRec[k][1], m02 = sRec[k][2];
            float m10 = sRec[k][3], m11 = sRec[k][4], m12 = sRec[k][5];
            float m20 = sRec[k][6], m21 = sRec[k][7], m22 = sRec[k][8];
            int   shm = __float_as_int(sRec[k][9]);
            float scm = sRec[k][10];
            int   pkm = __float_as_int(sRec[k][11]);

            float c00 = p00*m00 + p01*m10 + p02*m20;
            float c01 = p00*m01 + p01*m11 + p02*m21;
            float c02 = p00*m02 + p01*m12 + p02*m22;
            float c10 = p10*m00 + p11*m10 + p12*m20;
            float c11 = p10*m01 + p11*m11 + p12*m21;
            float c12 = p10*m02 + p11*m12 + p12*m22;
            float c20 = p20*m00 + p21*m10 + p22*m20;
            float c21 = p20*m01 + p21*m11 + p22*m21;
            float c22 = p20*m02 + p21*m12 + p22*m22;

            scT += scm + sTrans[lastT * 3 + (pkm & 255)];
            lastT = pkm >> 8;
            seT  += shm;
            p00=c00; p01=c01; p02=c02; p10=c10; p11=c11; p12=c12;
            p20=c20; p21=c21; p22=c22;
            RENORMP;
        }
        // fold own (wave 7) record from registers
        {
            float c00 = p00*a00 + p01*a10 + p02*a20;
            float c01 = p00*a01 + p01*a11 + p02*a21;
            float c02 = p00*a02 + p01*a12 + p02*a22;
            float c10 = p10*a00 + p11*a10 + p12*a20;
            float c11 = p10*a01 + p11*a11 + p12*a21;
            float c12 = p10*a02 + p11*a12 + p12*a22;
            float c20 = p20*a00 + p21*a10 + p22*a20;
            float c21 = p20*a01 + p21*a11 + p22*a21;
            float c22 = p20*a02 + p21*a12 + p22*a22;

            scT += score + sTrans[lastT * 3 + (fp & 255)];
            seT += se;
            p00=c00; p01=c01; p02=c02; p10=c10; p11=c11; p12=c12;
            p20=c20; p21=c21; p22=c22;
        }
        // alpha_T = v . P (row-vector times total product), value * 2^seT
        float w0 = sV[0], w1 = sV[1], w2 = sV[2];
        float n0 = w0*p00 + w1*p10 + w2*p20;
        float n1 = w0*p01 + w1*p11 + w2*p21;
        float n2 = w0*p02 + w1*p12 + w2*p22;
        float logz = logf(n0 + n1 + n2) + (float)seT * LN2;
        ws[b] = logz - scT;            // per-batch nll
#undef RENORMP
    }

#undef MATSTEP
#undef RENORM
#undef FOLD_ROUND
}

// ---------------------------------------------------------------------------
// Final reduction: one block sums the 2048 per-batch nll values.
// ---------------------------------------------------------------------------
__global__ __launch_bounds__(256) void crf_reduce(
    const float* __restrict__ ws, float* __restrict__ out)
{
    int tid = threadIdx.x;
    float s = 0.f;
#pragma unroll
    for (int k = 0; k < BB / 256; ++k) s += ws[k * 256 + tid];
    for (int off = 32; off > 0; off >>= 1) s += __shfl_down(s, off, 64);
    __shared__ float sP[4];
    if ((tid & 63) == 0) sP[tid >> 6] = s;
    __syncthreads();
    if (tid == 0) out[0] = sP[0] + sP[1] + sP[2] + sP[3];
}

extern "C" void kernel_launch(void* const* d_in, const int* in_sizes, int n_in,
                              void* d_out, int out_size, void* d_ws, size_t ws_size,
                              hipStream_t stream) {
    const float* logits = (const float*)d_in[0];
    const float* trans  = (const float*)d_in[1];
    const int*   tags   = (const int*)d_in[2];
    float* out = (float*)d_out;
    float* ws  = (float*)d_ws;

    crf_pass1<<<dim3(BB), dim3(512), 0, stream>>>(logits, trans, tags, ws);
    crf_reduce<<<dim3(1), dim3(256), 0, stream>>>(ws, out);
}